// Round 1
// baseline (534.698 us; speedup 1.0000x reference)
//
#include <hip/hip_runtime.h>
#include <hip/hip_bf16.h>

#define N_NODES 8192
#define N_EDGES 262144

// ---------------- CSR build ----------------

__global__ __launch_bounds__(256) void hist_kernel(const int* __restrict__ dst, int* __restrict__ deg) {
    int e = blockIdx.x * 256 + threadIdx.x;
    if (e < N_EDGES) atomicAdd(&deg[dst[e]], 1);
}

__global__ __launch_bounds__(1024) void scan_kernel(const int* __restrict__ deg, int* __restrict__ offs) {
    __shared__ int sums[1024];
    int t = threadIdx.x;
    int v[8];
    int s = 0;
#pragma unroll
    for (int i = 0; i < 8; i++) { v[i] = deg[t * 8 + i]; s += v[i]; }
    sums[t] = s;
    __syncthreads();
    for (int off = 1; off < 1024; off <<= 1) {
        int x = (t >= off) ? sums[t - off] : 0;
        __syncthreads();
        sums[t] += x;
        __syncthreads();
    }
    int ex = (t == 0) ? 0 : sums[t - 1];
#pragma unroll
    for (int i = 0; i < 8; i++) { offs[t * 8 + i] = ex; ex += v[i]; }
    if (t == 1023) offs[N_NODES] = ex;
}

__global__ __launch_bounds__(256) void scatter_kernel(const int* __restrict__ src, const int* __restrict__ dst,
                                                      const int* __restrict__ offs, int* __restrict__ cur,
                                                      int* __restrict__ csr) {
    int e = blockIdx.x * 256 + threadIdx.x;
    if (e < N_EDGES) {
        int d = dst[e];
        int p = atomicAdd(&cur[d], 1);
        csr[offs[d] + p] = src[e];
    }
}

__global__ __launch_bounds__(256) void concat_w_kernel(const float* __restrict__ W2, const float* __restrict__ W3,
                                                       float* __restrict__ W23) {
    int i = blockIdx.x * 256 + threadIdx.x;  // 32768 total
    if (i < 16384) W23[i] = W2[i];
    else if (i < 32768) W23[i] = W3[i - 16384];
}

// ---------------- GEMM: C[M,N] = A[M,K] * B[N,K]^T, row-major ----------------

template <int BM, int BN, int BK, int TM, int TN>
__global__ __launch_bounds__(256) void gemm_nt(const float* __restrict__ A, const float* __restrict__ B,
                                               float* __restrict__ C, int M, int N, int K) {
    __shared__ float As[BK][BM + 4];
    __shared__ float Bs[BK][BN + 4];
    const int tid = threadIdx.x;
    const int tc = tid % (BN / TN);
    const int tr = tid / (BN / TN);
    const int m0 = blockIdx.x * BM;
    const int n0 = blockIdx.y * BN;
    float acc[TM][TN] = {};
    for (int k0 = 0; k0 < K; k0 += BK) {
        constexpr int A_LOADS = BM * BK / (256 * 4);
#pragma unroll
        for (int i = 0; i < A_LOADS; i++) {
            int idx = (tid + i * 256) * 4;
            int am = idx / BK, ak = idx % BK;
            float4 v = *(const float4*)&A[(size_t)(m0 + am) * K + k0 + ak];
            As[ak + 0][am] = v.x; As[ak + 1][am] = v.y; As[ak + 2][am] = v.z; As[ak + 3][am] = v.w;
        }
        constexpr int B_LOADS = BN * BK / (256 * 4);
#pragma unroll
        for (int i = 0; i < B_LOADS; i++) {
            int idx = (tid + i * 256) * 4;
            int bn = idx / BK, bk = idx % BK;
            float4 v = *(const float4*)&B[(size_t)(n0 + bn) * K + k0 + bk];
            Bs[bk + 0][bn] = v.x; Bs[bk + 1][bn] = v.y; Bs[bk + 2][bn] = v.z; Bs[bk + 3][bn] = v.w;
        }
        __syncthreads();
#pragma unroll
        for (int k = 0; k < BK; k++) {
            float a[TM], b[TN];
#pragma unroll
            for (int i = 0; i < TM; i += 4) *(float4*)&a[i] = *(const float4*)&As[k][tr * TM + i];
#pragma unroll
            for (int j = 0; j < TN; j += 4) *(float4*)&b[j] = *(const float4*)&Bs[k][tc * TN + j];
#pragma unroll
            for (int i = 0; i < TM; i++)
#pragma unroll
                for (int j = 0; j < TN; j++) acc[i][j] = fmaf(a[i], b[j], acc[i][j]);
        }
        __syncthreads();
    }
#pragma unroll
    for (int i = 0; i < TM; i++) {
#pragma unroll
        for (int j = 0; j < TN; j += 4) {
            float4 v = {acc[i][j], acc[i][j + 1], acc[i][j + 2], acc[i][j + 3]};
            *(float4*)&C[(size_t)(m0 + tr * TM + i) * N + n0 + tc * TN + j] = v;
        }
    }
}

// ---------------- Aggregation (CSR gather-sum), width 256, + bias + relu ----------------

__global__ __launch_bounds__(256) void agg_relu_kernel(const float* __restrict__ Y, const int* __restrict__ offs,
                                                       const int* __restrict__ csr, const float* __restrict__ bias,
                                                       float* __restrict__ out) {
    int node = blockIdx.x * 4 + (threadIdx.x >> 6);
    int lane = threadIdx.x & 63;
    int s = offs[node], e = offs[node + 1];
    float4 acc = {0.f, 0.f, 0.f, 0.f};
    for (int i = s; i < e; i++) {
        int u = csr[i];
        float4 v = *(const float4*)&Y[(size_t)u * 256 + lane * 4];
        acc.x += v.x; acc.y += v.y; acc.z += v.z; acc.w += v.w;
    }
    float4 b = *(const float4*)&bias[lane * 4];
    acc.x = fmaxf(acc.x + b.x, 0.f);
    acc.y = fmaxf(acc.y + b.y, 0.f);
    acc.z = fmaxf(acc.z + b.z, 0.f);
    acc.w = fmaxf(acc.w + b.w, 0.f);
    *(float4*)&out[(size_t)node * 256 + lane * 4] = acc;
}

// ---------------- Aggregation width 128 -> split mu/logvar with biases ----------------

__global__ __launch_bounds__(256) void agg_split_kernel(const float* __restrict__ Z, const int* __restrict__ offs,
                                                        const int* __restrict__ csr, const float* __restrict__ b2,
                                                        const float* __restrict__ b3, float* __restrict__ mu,
                                                        float* __restrict__ lv) {
    int node = blockIdx.x * 4 + (threadIdx.x >> 6);
    int lane = threadIdx.x & 63;
    int s = offs[node], e = offs[node + 1];
    float2 acc = {0.f, 0.f};
    for (int i = s; i < e; i++) {
        int u = csr[i];
        float2 v = *(const float2*)&Z[(size_t)u * 128 + lane * 2];
        acc.x += v.x; acc.y += v.y;
    }
    int col = lane * 2;
    if (col < 64) {
        acc.x += b2[col]; acc.y += b2[col + 1];
        *(float2*)&mu[(size_t)node * 64 + col] = acc;
    } else {
        col -= 64;
        acc.x += b3[col]; acc.y += b3[col + 1];
        *(float2*)&lv[(size_t)node * 64 + col] = acc;
    }
}

// ---------------- adj = sigmoid(Z Z^T), Z = [8192, 64] ----------------

__global__ __launch_bounds__(256) void adj_kernel(const float* __restrict__ Zr, float* __restrict__ out) {
    __shared__ float As[64][128 + 4];
    __shared__ float Bs[64][128 + 4];
    const int tid = threadIdx.x;
    const int m0 = blockIdx.x * 128;
    const int n0 = blockIdx.y * 128;
#pragma unroll
    for (int i = 0; i < 8; i++) {
        int idx = (tid + i * 256) * 4;
        int r = idx >> 6, k = idx & 63;
        float4 v = *(const float4*)&Zr[(size_t)(m0 + r) * 64 + k];
        As[k + 0][r] = v.x; As[k + 1][r] = v.y; As[k + 2][r] = v.z; As[k + 3][r] = v.w;
        float4 w = *(const float4*)&Zr[(size_t)(n0 + r) * 64 + k];
        Bs[k + 0][r] = w.x; Bs[k + 1][r] = w.y; Bs[k + 2][r] = w.z; Bs[k + 3][r] = w.w;
    }
    __syncthreads();
    const int tc = tid % 16, tr = tid / 16;
    float acc[8][8] = {};
#pragma unroll
    for (int k = 0; k < 64; k++) {
        float a[8], b[8];
        *(float4*)&a[0] = *(const float4*)&As[k][tr * 8];
        *(float4*)&a[4] = *(const float4*)&As[k][tr * 8 + 4];
        *(float4*)&b[0] = *(const float4*)&Bs[k][tc * 8];
        *(float4*)&b[4] = *(const float4*)&Bs[k][tc * 8 + 4];
#pragma unroll
        for (int i = 0; i < 8; i++)
#pragma unroll
            for (int j = 0; j < 8; j++) acc[i][j] = fmaf(a[i], b[j], acc[i][j]);
    }
#pragma unroll
    for (int i = 0; i < 8; i++) {
        size_t row = (size_t)(m0 + tr * 8 + i) * N_NODES + n0 + tc * 8;
#pragma unroll
        for (int j = 0; j < 8; j += 4) {
            float4 v;
            v.x = 1.0f / (1.0f + __expf(-acc[i][j + 0]));
            v.y = 1.0f / (1.0f + __expf(-acc[i][j + 1]));
            v.z = 1.0f / (1.0f + __expf(-acc[i][j + 2]));
            v.w = 1.0f / (1.0f + __expf(-acc[i][j + 3]));
            *(float4*)&out[row + j] = v;
        }
    }
}

// ---------------- launch ----------------

extern "C" void kernel_launch(void* const* d_in, const int* in_sizes, int n_in,
                              void* d_out, int out_size, void* d_ws, size_t ws_size,
                              hipStream_t stream) {
    const float* X  = (const float*)d_in[0];
    const int*   src = (const int*)d_in[1];
    const int*   dst = (const int*)d_in[2];
    const float* W1 = (const float*)d_in[3];
    const float* b1 = (const float*)d_in[4];
    const float* W2 = (const float*)d_in[5];
    const float* b2 = (const float*)d_in[6];
    const float* W3 = (const float*)d_in[7];
    const float* b3 = (const float*)d_in[8];

    float* out    = (float*)d_out;
    float* adj    = out;                                      // [8192*8192]
    float* mu_out = out + (size_t)N_NODES * N_NODES;          // [8192*64]
    float* lv_out = mu_out + (size_t)N_NODES * 64;            // [8192*64]

    // Scratch carved inside the adj region (268 MB; only written by the final kernel).
    int* ibase = (int*)d_out;
    int* deg  = ibase;             // 8192
    int* cur  = ibase + 8192;      // 8192
    int* offs = ibase + 16384;     // 8193
    int* csr  = ibase + 24584;     // 262144
    float* fbase  = (float*)d_out;
    float* Y1     = fbase + 286728;              // 8192*256
    float* hidden = Y1 + (size_t)N_NODES * 256;  // 8192*256
    float* Z      = hidden + (size_t)N_NODES * 256;  // 8192*128
    float* W23    = Z + (size_t)N_NODES * 128;   // 128*256

    hipMemsetAsync(deg, 0, 2 * N_NODES * sizeof(int), stream);  // deg + cur
    hist_kernel<<<N_EDGES / 256, 256, 0, stream>>>(dst, deg);
    scan_kernel<<<1, 1024, 0, stream>>>(deg, offs);
    scatter_kernel<<<N_EDGES / 256, 256, 0, stream>>>(src, dst, offs, cur, csr);
    concat_w_kernel<<<128, 256, 0, stream>>>(W2, W3, W23);

    // Y1 = X @ W1^T : [8192,512]x[256,512]^T -> [8192,256]
    gemm_nt<128, 64, 16, 8, 4><<<dim3(8192 / 128, 256 / 64), 256, 0, stream>>>(X, W1, Y1, 8192, 256, 512);
    // hidden = relu(agg(Y1) + b1)
    agg_relu_kernel<<<N_NODES / 4, 256, 0, stream>>>(Y1, offs, csr, b1, hidden);
    // Z = hidden @ W23^T : [8192,256]x[128,256]^T -> [8192,128]
    gemm_nt<64, 64, 16, 4, 4><<<dim3(8192 / 64, 128 / 64), 256, 0, stream>>>(hidden, W23, Z, 8192, 128, 256);
    // mu/logvar = agg(Z) + b2/b3 (split)
    agg_split_kernel<<<N_NODES / 4, 256, 0, stream>>>(Z, offs, csr, b2, b3, mu_out, lv_out);
    // adj = sigmoid(mu @ mu^T)
    adj_kernel<<<dim3(64, 64), 256, 0, stream>>>(mu_out, adj);
}

// Round 3
// 419.921 us; speedup vs baseline: 1.2733x; 1.2733x over previous
//
#include <hip/hip_runtime.h>
#include <hip/hip_bf16.h>
#include <type_traits>

#define N_NODES 8192
#define N_EDGES 262144

typedef __attribute__((ext_vector_type(8))) short short8v;
typedef __attribute__((ext_vector_type(4))) float float4v;

static __device__ __forceinline__ unsigned short f2bf(float f) {
    unsigned u = __float_as_uint(f);
    unsigned r = (u + 0x7FFF + ((u >> 16) & 1)) >> 16;   // RNE, finite values
    return (unsigned short)r;
}
static __device__ __forceinline__ float bf2f(unsigned short h) {
    return __uint_as_float(((unsigned)h) << 16);
}

// ---------------- CSR build ----------------

__global__ __launch_bounds__(256) void hist_kernel(const int* __restrict__ dst, int* __restrict__ deg) {
    int e = blockIdx.x * 256 + threadIdx.x;
    if (e < N_EDGES) atomicAdd(&deg[dst[e]], 1);
}

__global__ __launch_bounds__(1024) void scan_kernel(const int* __restrict__ deg, int* __restrict__ offs) {
    __shared__ int sums[1024];
    int t = threadIdx.x;
    int v[8];
    int s = 0;
#pragma unroll
    for (int i = 0; i < 8; i++) { v[i] = deg[t * 8 + i]; s += v[i]; }
    sums[t] = s;
    __syncthreads();
    for (int off = 1; off < 1024; off <<= 1) {
        int x = (t >= off) ? sums[t - off] : 0;
        __syncthreads();
        sums[t] += x;
        __syncthreads();
    }
    int ex = (t == 0) ? 0 : sums[t - 1];
#pragma unroll
    for (int i = 0; i < 8; i++) { offs[t * 8 + i] = ex; ex += v[i]; }
    if (t == 1023) offs[N_NODES] = ex;
}

__global__ __launch_bounds__(256) void scatter_kernel(const int* __restrict__ src, const int* __restrict__ dst,
                                                      const int* __restrict__ offs, int* __restrict__ cur,
                                                      int* __restrict__ csr) {
    int e = blockIdx.x * 256 + threadIdx.x;
    if (e < N_EDGES) {
        int d = dst[e];
        int p = atomicAdd(&cur[d], 1);
        csr[offs[d] + p] = src[e];
    }
}

__global__ __launch_bounds__(256) void concat_w_kernel(const float* __restrict__ W2, const float* __restrict__ W3,
                                                       float* __restrict__ W23) {
    int i = blockIdx.x * 256 + threadIdx.x;  // 32768 total
    if (i < 16384) W23[i] = W2[i];
    else if (i < 32768) W23[i] = W3[i - 16384];
}

// ---------------- GEMM: C[M,N] = A[M,K] * B[N,K]^T, row-major, OutT in {float, bf16-as-ushort} ----------------

template <int BM, int BN, int BK, int TM, int TN, bool BF16_OUT>
__global__ __launch_bounds__(256) void gemm_nt(const float* __restrict__ A, const float* __restrict__ B,
                                               void* __restrict__ Cv, int M, int N, int K) {
    __shared__ float As[BK][BM + 4];
    __shared__ float Bs[BK][BN + 4];
    const int tid = threadIdx.x;
    const int tc = tid % (BN / TN);
    const int tr = tid / (BN / TN);
    const int m0 = blockIdx.x * BM;
    const int n0 = blockIdx.y * BN;
    float acc[TM][TN] = {};
    for (int k0 = 0; k0 < K; k0 += BK) {
        constexpr int A_LOADS = BM * BK / (256 * 4);
#pragma unroll
        for (int i = 0; i < A_LOADS; i++) {
            int idx = (tid + i * 256) * 4;
            int am = idx / BK, ak = idx % BK;
            float4 v = *(const float4*)&A[(size_t)(m0 + am) * K + k0 + ak];
            As[ak + 0][am] = v.x; As[ak + 1][am] = v.y; As[ak + 2][am] = v.z; As[ak + 3][am] = v.w;
        }
        constexpr int B_LOADS = BN * BK / (256 * 4);
#pragma unroll
        for (int i = 0; i < B_LOADS; i++) {
            int idx = (tid + i * 256) * 4;
            int bn = idx / BK, bk = idx % BK;
            float4 v = *(const float4*)&B[(size_t)(n0 + bn) * K + k0 + bk];
            Bs[bk + 0][bn] = v.x; Bs[bk + 1][bn] = v.y; Bs[bk + 2][bn] = v.z; Bs[bk + 3][bn] = v.w;
        }
        __syncthreads();
#pragma unroll
        for (int k = 0; k < BK; k++) {
            float a[TM], b[TN];
#pragma unroll
            for (int i = 0; i < TM; i += 4) *(float4*)&a[i] = *(const float4*)&As[k][tr * TM + i];
#pragma unroll
            for (int j = 0; j < TN; j += 4) *(float4*)&b[j] = *(const float4*)&Bs[k][tc * TN + j];
#pragma unroll
            for (int i = 0; i < TM; i++)
#pragma unroll
                for (int j = 0; j < TN; j++) acc[i][j] = fmaf(a[i], b[j], acc[i][j]);
        }
        __syncthreads();
    }
#pragma unroll
    for (int i = 0; i < TM; i++) {
        size_t row = (size_t)(m0 + tr * TM + i) * N + n0 + tc * TN;
        if constexpr (BF16_OUT) {
            unsigned short* C = (unsigned short*)Cv;
#pragma unroll
            for (int j = 0; j < TN; j += 4) {
                ushort4 v;
                v.x = f2bf(acc[i][j]); v.y = f2bf(acc[i][j + 1]);
                v.z = f2bf(acc[i][j + 2]); v.w = f2bf(acc[i][j + 3]);
                *(ushort4*)&C[row + j] = v;
            }
        } else {
            float* C = (float*)Cv;
#pragma unroll
            for (int j = 0; j < TN; j += 4) {
                float4 v = {acc[i][j], acc[i][j + 1], acc[i][j + 2], acc[i][j + 3]};
                *(float4*)&C[row + j] = v;
            }
        }
    }
}

// ---------------- Aggregation (CSR gather-sum) over bf16 Y1 [N,256], + bias + relu -> fp32 hidden ----------------

__global__ __launch_bounds__(256) void agg_relu_kernel(const unsigned short* __restrict__ Yb,
                                                       const int* __restrict__ offs,
                                                       const int* __restrict__ csr, const float* __restrict__ bias,
                                                       float* __restrict__ out) {
    int node = blockIdx.x * 4 + (threadIdx.x >> 6);
    int lane = threadIdx.x & 63;
    int s = offs[node], e = offs[node + 1];
    float4 acc = {0.f, 0.f, 0.f, 0.f};
    for (int i = s; i < e; i++) {
        int u = csr[i];
        ushort4 v = *(const ushort4*)&Yb[(size_t)u * 256 + lane * 4];
        acc.x += bf2f(v.x); acc.y += bf2f(v.y); acc.z += bf2f(v.z); acc.w += bf2f(v.w);
    }
    float4 b = *(const float4*)&bias[lane * 4];
    acc.x = fmaxf(acc.x + b.x, 0.f);
    acc.y = fmaxf(acc.y + b.y, 0.f);
    acc.z = fmaxf(acc.z + b.z, 0.f);
    acc.w = fmaxf(acc.w + b.w, 0.f);
    *(float4*)&out[(size_t)node * 256 + lane * 4] = acc;
}

// ---------------- Aggregation over bf16 Z [N,128] -> mu/logvar fp32 (+bias) and bf16 zb [N,64] ----------------

__global__ __launch_bounds__(256) void agg_split_kernel(const unsigned short* __restrict__ Zb,
                                                        const int* __restrict__ offs,
                                                        const int* __restrict__ csr, const float* __restrict__ b2,
                                                        const float* __restrict__ b3, float* __restrict__ mu,
                                                        float* __restrict__ lv, unsigned short* __restrict__ zb) {
    int node = blockIdx.x * 4 + (threadIdx.x >> 6);
    int lane = threadIdx.x & 63;
    int s = offs[node], e = offs[node + 1];
    float2 acc = {0.f, 0.f};
    for (int i = s; i < e; i++) {
        int u = csr[i];
        ushort2 v = *(const ushort2*)&Zb[(size_t)u * 128 + lane * 2];
        acc.x += bf2f(v.x); acc.y += bf2f(v.y);
    }
    int col = lane * 2;
    if (col < 64) {
        acc.x += b2[col]; acc.y += b2[col + 1];
        *(float2*)&mu[(size_t)node * 64 + col] = acc;
        ushort2 q = {f2bf(acc.x), f2bf(acc.y)};
        *(ushort2*)&zb[(size_t)node * 64 + col] = q;
    } else {
        col -= 64;
        acc.x += b3[col]; acc.y += b3[col + 1];
        *(float2*)&lv[(size_t)node * 64 + col] = acc;
    }
}

// ---------------- adj = sigmoid(Z Z^T) via bf16 MFMA; zb = [8192, 64] bf16 ----------------
// mfma_f32_16x16x32_bf16: A[m=lane&15][k=(lane>>4)*8+j]; C/D: col=lane&15, row=(lane>>4)*4+reg.

__global__ __launch_bounds__(256) void adj_mfma_kernel(const unsigned short* __restrict__ zb,
                                                       float* __restrict__ out) {
    const int tid = threadIdx.x;
    const int lane = tid & 63;
    const int wid = tid >> 6;
    const int waveM = wid >> 1, waveN = wid & 1;
    const int m_base = blockIdx.x * 128 + waveM * 64;
    const int n_base = blockIdx.y * 128 + waveN * 64;
    const int r = lane & 15;         // row/col within 16-tile
    const int q = lane >> 4;         // k-group (0..3)

    short8v a[4][2], b[4][2];
#pragma unroll
    for (int i = 0; i < 4; i++)
#pragma unroll
        for (int s = 0; s < 2; s++) {
            a[i][s] = *(const short8v*)&zb[(size_t)(m_base + i * 16 + r) * 64 + s * 32 + q * 8];
            b[i][s] = *(const short8v*)&zb[(size_t)(n_base + i * 16 + r) * 64 + s * 32 + q * 8];
        }

    float4v acc[4][4] = {};
#pragma unroll
    for (int s = 0; s < 2; s++)
#pragma unroll
        for (int i = 0; i < 4; i++)
#pragma unroll
            for (int j = 0; j < 4; j++)
                acc[i][j] = __builtin_amdgcn_mfma_f32_16x16x32_bf16(a[i][s], b[j][s], acc[i][j], 0, 0, 0);

#pragma unroll
    for (int i = 0; i < 4; i++)
#pragma unroll
        for (int j = 0; j < 4; j++) {
            int col = n_base + j * 16 + r;
#pragma unroll
            for (int t = 0; t < 4; t++) {
                int row = m_base + i * 16 + q * 4 + t;
                float v = 1.0f / (1.0f + __expf(-acc[i][j][t]));
                out[(size_t)row * N_NODES + col] = v;
            }
        }
}

// ---------------- launch ----------------

extern "C" void kernel_launch(void* const* d_in, const int* in_sizes, int n_in,
                              void* d_out, int out_size, void* d_ws, size_t ws_size,
                              hipStream_t stream) {
    const float* X   = (const float*)d_in[0];
    const int*   src = (const int*)d_in[1];
    const int*   dst = (const int*)d_in[2];
    const float* W1  = (const float*)d_in[3];
    const float* b1  = (const float*)d_in[4];
    const float* W2  = (const float*)d_in[5];
    const float* b2  = (const float*)d_in[6];
    const float* W3  = (const float*)d_in[7];
    const float* b3  = (const float*)d_in[8];

    float* out    = (float*)d_out;
    float* adj    = out;                              // [8192*8192]
    float* mu_out = out + (size_t)N_NODES * N_NODES;  // [8192*64]
    float* lv_out = mu_out + (size_t)N_NODES * 64;    // [8192*64]

    // Scratch in d_ws. NOTE: offs needs 8193 ints (32772 B) — csr must start
    // past byte 98308 (R2 bug: csr[0] clobbered offs[8192]).
    char* ws = (char*)d_ws;
    int* deg             = (int*)(ws + 0);                    // 8192 ints
    int* cur             = (int*)(ws + 32768);                // 8192 ints
    int* offs            = (int*)(ws + 65536);                // 8193 ints -> ends 98308
    int* csr             = (int*)(ws + 98816);                // 262144 ints -> ends 1147392
    float* W23           = (float*)(ws + 1179648);            // 128*256 f32 -> ends 1310720
    unsigned short* Y1b  = (unsigned short*)(ws + 1310720);   // 8192*256 bf16 -> ends 5505024
    float* hidden        = (float*)(ws + 5505024);            // 8192*256 f32 -> ends 13893632
    unsigned short* Zb   = (unsigned short*)(ws + 13893632);  // 8192*128 bf16 -> ends 15990784
    unsigned short* zb   = (unsigned short*)(ws + 15990784);  // 8192*64 bf16 -> ends 17039360

    hipMemsetAsync(deg, 0, 2 * N_NODES * sizeof(int), stream);  // deg + cur
    hist_kernel<<<N_EDGES / 256, 256, 0, stream>>>(dst, deg);
    scan_kernel<<<1, 1024, 0, stream>>>(deg, offs);
    scatter_kernel<<<N_EDGES / 256, 256, 0, stream>>>(src, dst, offs, cur, csr);
    concat_w_kernel<<<128, 256, 0, stream>>>(W2, W3, W23);

    // Y1b = bf16(X @ W1^T) : [8192,512]x[256,512]^T -> [8192,256]
    gemm_nt<64, 64, 16, 4, 4, true><<<dim3(128, 4), 256, 0, stream>>>(X, W1, Y1b, 8192, 256, 512);
    // hidden = relu(agg(Y1b) + b1)
    agg_relu_kernel<<<N_NODES / 4, 256, 0, stream>>>(Y1b, offs, csr, b1, hidden);
    // Zb = bf16(hidden @ W23^T) : [8192,256]x[128,256]^T -> [8192,128]
    gemm_nt<64, 64, 16, 4, 4, true><<<dim3(128, 2), 256, 0, stream>>>(hidden, W23, Zb, 8192, 128, 256);
    // mu/logvar = agg(Zb) + b2/b3 (split); zb = bf16(mu)
    agg_split_kernel<<<N_NODES / 4, 256, 0, stream>>>(Zb, offs, csr, b2, b3, mu_out, lv_out, zb);
    // adj = sigmoid(zb @ zb^T) via MFMA
    adj_mfma_kernel<<<dim3(64, 64), 256, 0, stream>>>(zb, adj);
}

// Round 4
// 383.487 us; speedup vs baseline: 1.3943x; 1.0950x over previous
//
#include <hip/hip_runtime.h>
#include <hip/hip_bf16.h>

#define N_NODES 8192
#define N_EDGES 262144

typedef __attribute__((ext_vector_type(8))) short short8v;
typedef __attribute__((ext_vector_type(4))) float float4v;

static __device__ __forceinline__ unsigned short f2bf(float f) {
    unsigned u = __float_as_uint(f);
    unsigned r = (u + 0x7FFF + ((u >> 16) & 1)) >> 16;   // RNE, finite values
    return (unsigned short)r;
}
static __device__ __forceinline__ float bf2f(unsigned short h) {
    return __uint_as_float(((unsigned)h) << 16);
}

// ---------------- CSR build ----------------

__global__ __launch_bounds__(256) void hist_kernel(const int* __restrict__ dst, int* __restrict__ deg) {
    int e = blockIdx.x * 256 + threadIdx.x;
    if (e < N_EDGES) atomicAdd(&deg[dst[e]], 1);
}

__global__ __launch_bounds__(1024) void scan_kernel(const int* __restrict__ deg, int* __restrict__ offs) {
    __shared__ int sums[1024];
    int t = threadIdx.x;
    int v[8];
    int s = 0;
#pragma unroll
    for (int i = 0; i < 8; i++) { v[i] = deg[t * 8 + i]; s += v[i]; }
    sums[t] = s;
    __syncthreads();
    for (int off = 1; off < 1024; off <<= 1) {
        int x = (t >= off) ? sums[t - off] : 0;
        __syncthreads();
        sums[t] += x;
        __syncthreads();
    }
    int ex = (t == 0) ? 0 : sums[t - 1];
#pragma unroll
    for (int i = 0; i < 8; i++) { offs[t * 8 + i] = ex; ex += v[i]; }
    if (t == 1023) offs[N_NODES] = ex;
}

__global__ __launch_bounds__(256) void scatter_kernel(const int* __restrict__ src, const int* __restrict__ dst,
                                                      const int* __restrict__ offs, int* __restrict__ cur,
                                                      int* __restrict__ csr) {
    int e = blockIdx.x * 256 + threadIdx.x;
    if (e < N_EDGES) {
        int d = dst[e];
        int p = atomicAdd(&cur[d], 1);
        csr[offs[d] + p] = src[e];
    }
}

// ---------------- fused fp32 -> bf16 casts: X, W1, W2|W3 (concat) ----------------

__global__ __launch_bounds__(256) void prep_cast_kernel(const float* __restrict__ X, const float* __restrict__ W1,
                                                        const float* __restrict__ W2, const float* __restrict__ W3,
                                                        unsigned short* __restrict__ Xb,
                                                        unsigned short* __restrict__ W1b,
                                                        unsigned short* __restrict__ W23b) {
    int i4 = (blockIdx.x * 256 + threadIdx.x) * 4;
    const float* srcp;
    unsigned short* dstp;
    int off;
    if (i4 < 4194304)      { srcp = X;  dstp = Xb;           off = i4; }
    else if (i4 < 4325376) { srcp = W1; dstp = W1b;          off = i4 - 4194304; }
    else if (i4 < 4341760) { srcp = W2; dstp = W23b;         off = i4 - 4325376; }
    else                   { srcp = W3; dstp = W23b + 16384; off = i4 - 4341760; }
    float4 v = *(const float4*)&srcp[off];
    ushort4 o = {f2bf(v.x), f2bf(v.y), f2bf(v.z), f2bf(v.w)};
    *(ushort4*)&dstp[off] = o;
}

// ---------------- MFMA GEMM: C[M,N] = A[M,K] @ B[N,K]^T, all row-major bf16 ----------------
// Direct global fragment loads (layout HW-proven by adj kernel):
//   A[m=lane&15][k=(lane>>4)*8+j], B mirrors A; C/D: col=lane&15, row=(lane>>4)*4+reg.
// Block = 4 waves. Wave tile (MI*16) x (NJ*16); WN waves along N, 4/WN along M.

template <int MI, int NJ, int WN>
__global__ __launch_bounds__(256) void gemm_nt_mfma(const unsigned short* __restrict__ A,
                                                    const unsigned short* __restrict__ B,
                                                    unsigned short* __restrict__ C,
                                                    int N, int K) {
    constexpr int MW = 4 / WN;
    const int tid = threadIdx.x;
    const int lane = tid & 63;
    const int w = tid >> 6;
    const int r = lane & 15, q = lane >> 4;
    const int m0 = blockIdx.x * (MI * 16 * MW) + (w / WN) * (MI * 16);
    const int n0 = blockIdx.y * (NJ * 16 * WN) + (w % WN) * (NJ * 16);
    float4v acc[MI][NJ] = {};
    for (int k = 0; k < K; k += 32) {
        short8v a[MI], b[NJ];
#pragma unroll
        for (int i = 0; i < MI; i++)
            a[i] = *(const short8v*)&A[(size_t)(m0 + i * 16 + r) * K + k + q * 8];
#pragma unroll
        for (int j = 0; j < NJ; j++)
            b[j] = *(const short8v*)&B[(size_t)(n0 + j * 16 + r) * K + k + q * 8];
#pragma unroll
        for (int i = 0; i < MI; i++)
#pragma unroll
            for (int j = 0; j < NJ; j++)
                acc[i][j] = __builtin_amdgcn_mfma_f32_16x16x32_bf16(a[i], b[j], acc[i][j], 0, 0, 0);
    }
#pragma unroll
    for (int i = 0; i < MI; i++)
#pragma unroll
        for (int j = 0; j < NJ; j++) {
            int col = n0 + j * 16 + r;
#pragma unroll
            for (int t = 0; t < 4; t++) {
                int row = m0 + i * 16 + q * 4 + t;
                C[(size_t)row * N + col] = f2bf(acc[i][j][t]);
            }
        }
}

// ---------------- Aggregation (CSR gather-sum) over bf16 Y1 [N,256], + bias + relu -> bf16 hidden ----------------

__global__ __launch_bounds__(256) void agg_relu_kernel(const unsigned short* __restrict__ Yb,
                                                       const int* __restrict__ offs,
                                                       const int* __restrict__ csr, const float* __restrict__ bias,
                                                       unsigned short* __restrict__ out) {
    int node = blockIdx.x * 4 + (threadIdx.x >> 6);
    int lane = threadIdx.x & 63;
    int s = offs[node], e = offs[node + 1];
    float4 acc = {0.f, 0.f, 0.f, 0.f};
    int i = s;
    for (; i + 1 < e; i += 2) {
        int u0 = csr[i], u1 = csr[i + 1];
        ushort4 v0 = *(const ushort4*)&Yb[(size_t)u0 * 256 + lane * 4];
        ushort4 v1 = *(const ushort4*)&Yb[(size_t)u1 * 256 + lane * 4];
        acc.x += bf2f(v0.x) + bf2f(v1.x);
        acc.y += bf2f(v0.y) + bf2f(v1.y);
        acc.z += bf2f(v0.z) + bf2f(v1.z);
        acc.w += bf2f(v0.w) + bf2f(v1.w);
    }
    if (i < e) {
        int u = csr[i];
        ushort4 v = *(const ushort4*)&Yb[(size_t)u * 256 + lane * 4];
        acc.x += bf2f(v.x); acc.y += bf2f(v.y); acc.z += bf2f(v.z); acc.w += bf2f(v.w);
    }
    float4 b = *(const float4*)&bias[lane * 4];
    ushort4 o;
    o.x = f2bf(fmaxf(acc.x + b.x, 0.f));
    o.y = f2bf(fmaxf(acc.y + b.y, 0.f));
    o.z = f2bf(fmaxf(acc.z + b.z, 0.f));
    o.w = f2bf(fmaxf(acc.w + b.w, 0.f));
    *(ushort4*)&out[(size_t)node * 256 + lane * 4] = o;
}

// ---------------- Aggregation over bf16 Z [N,128] -> mu/logvar fp32 (+bias) and bf16 zb [N,64] ----------------

__global__ __launch_bounds__(256) void agg_split_kernel(const unsigned short* __restrict__ Zb,
                                                        const int* __restrict__ offs,
                                                        const int* __restrict__ csr, const float* __restrict__ b2,
                                                        const float* __restrict__ b3, float* __restrict__ mu,
                                                        float* __restrict__ lv, unsigned short* __restrict__ zb) {
    int node = blockIdx.x * 4 + (threadIdx.x >> 6);
    int lane = threadIdx.x & 63;
    int s = offs[node], e = offs[node + 1];
    float2 acc = {0.f, 0.f};
    int i = s;
    for (; i + 1 < e; i += 2) {
        int u0 = csr[i], u1 = csr[i + 1];
        ushort2 v0 = *(const ushort2*)&Zb[(size_t)u0 * 128 + lane * 2];
        ushort2 v1 = *(const ushort2*)&Zb[(size_t)u1 * 128 + lane * 2];
        acc.x += bf2f(v0.x) + bf2f(v1.x);
        acc.y += bf2f(v0.y) + bf2f(v1.y);
    }
    if (i < e) {
        int u = csr[i];
        ushort2 v = *(const ushort2*)&Zb[(size_t)u * 128 + lane * 2];
        acc.x += bf2f(v.x); acc.y += bf2f(v.y);
    }
    int col = lane * 2;
    if (col < 64) {
        acc.x += b2[col]; acc.y += b2[col + 1];
        *(float2*)&mu[(size_t)node * 64 + col] = acc;
        ushort2 q = {f2bf(acc.x), f2bf(acc.y)};
        *(ushort2*)&zb[(size_t)node * 64 + col] = q;
    } else {
        col -= 64;
        acc.x += b3[col]; acc.y += b3[col + 1];
        *(float2*)&lv[(size_t)node * 64 + col] = acc;
    }
}

// ---------------- adj = sigmoid(z z^T) via bf16 MFMA; zb = [8192, 64] bf16 ----------------

__global__ __launch_bounds__(256) void adj_mfma_kernel(const unsigned short* __restrict__ zb,
                                                       float* __restrict__ out) {
    const int tid = threadIdx.x;
    const int lane = tid & 63;
    const int wid = tid >> 6;
    const int waveM = wid >> 1, waveN = wid & 1;
    const int m_base = blockIdx.x * 128 + waveM * 64;
    const int n_base = blockIdx.y * 128 + waveN * 64;
    const int r = lane & 15;
    const int q = lane >> 4;

    short8v a[4][2], b[4][2];
#pragma unroll
    for (int i = 0; i < 4; i++)
#pragma unroll
        for (int s = 0; s < 2; s++) {
            a[i][s] = *(const short8v*)&zb[(size_t)(m_base + i * 16 + r) * 64 + s * 32 + q * 8];
            b[i][s] = *(const short8v*)&zb[(size_t)(n_base + i * 16 + r) * 64 + s * 32 + q * 8];
        }

    float4v acc[4][4] = {};
#pragma unroll
    for (int s = 0; s < 2; s++)
#pragma unroll
        for (int i = 0; i < 4; i++)
#pragma unroll
            for (int j = 0; j < 4; j++)
                acc[i][j] = __builtin_amdgcn_mfma_f32_16x16x32_bf16(a[i][s], b[j][s], acc[i][j], 0, 0, 0);

#pragma unroll
    for (int i = 0; i < 4; i++)
#pragma unroll
        for (int j = 0; j < 4; j++) {
            int col = n_base + j * 16 + r;
#pragma unroll
            for (int t = 0; t < 4; t++) {
                int row = m_base + i * 16 + q * 4 + t;
                float v = 1.0f / (1.0f + __expf(-acc[i][j][t]));
                out[(size_t)row * N_NODES + col] = v;
            }
        }
}

// ---------------- launch ----------------

extern "C" void kernel_launch(void* const* d_in, const int* in_sizes, int n_in,
                              void* d_out, int out_size, void* d_ws, size_t ws_size,
                              hipStream_t stream) {
    const float* X   = (const float*)d_in[0];
    const int*   src = (const int*)d_in[1];
    const int*   dst = (const int*)d_in[2];
    const float* W1  = (const float*)d_in[3];
    const float* b1  = (const float*)d_in[4];
    const float* W2  = (const float*)d_in[5];
    const float* b2  = (const float*)d_in[6];
    const float* W3  = (const float*)d_in[7];
    const float* b3  = (const float*)d_in[8];

    float* out    = (float*)d_out;
    float* adj    = out;                              // [8192*8192]
    float* mu_out = out + (size_t)N_NODES * N_NODES;  // [8192*64]
    float* lv_out = mu_out + (size_t)N_NODES * 64;    // [8192*64]

    // Workspace allocator: 1 KiB-aligned carve-outs (R2 lesson: no hand arithmetic).
    char* ws = (char*)d_ws;
    size_t off = 0;
    auto alloc = [&](size_t bytes) -> void* {
        void* p = ws + off;
        off += (bytes + 1023) & ~(size_t)1023;
        return p;
    };
    int* deg            = (int*)alloc(N_NODES * 4);
    int* cur            = (int*)alloc(N_NODES * 4);
    int* offs           = (int*)alloc((N_NODES + 1) * 4);
    int* csr            = (int*)alloc(N_EDGES * 4);
    unsigned short* Xb  = (unsigned short*)alloc((size_t)N_NODES * 512 * 2);
    unsigned short* W1b = (unsigned short*)alloc(256 * 512 * 2);
    unsigned short* W23b= (unsigned short*)alloc(128 * 256 * 2);
    unsigned short* Y1b = (unsigned short*)alloc((size_t)N_NODES * 256 * 2);
    unsigned short* Hb  = (unsigned short*)alloc((size_t)N_NODES * 256 * 2);
    unsigned short* Zb  = (unsigned short*)alloc((size_t)N_NODES * 128 * 2);
    unsigned short* zb  = (unsigned short*)alloc((size_t)N_NODES * 64 * 2);

    hipMemsetAsync(deg, 0, 2 * N_NODES * sizeof(int), stream);  // deg + cur (adjacent)
    hist_kernel<<<N_EDGES / 256, 256, 0, stream>>>(dst, deg);
    scan_kernel<<<1, 1024, 0, stream>>>(deg, offs);
    scatter_kernel<<<N_EDGES / 256, 256, 0, stream>>>(src, dst, offs, cur, csr);
    prep_cast_kernel<<<4256, 256, 0, stream>>>(X, W1, W2, W3, Xb, W1b, W23b);

    // Y1b = bf16(Xb @ W1b^T) : [8192,512]x[256,512]^T -> [8192,256]
    gemm_nt_mfma<4, 2, 4><<<dim3(128, 2), 256, 0, stream>>>(Xb, W1b, Y1b, 256, 512);
    // Hb = bf16(relu(agg(Y1b) + b1))
    agg_relu_kernel<<<N_NODES / 4, 256, 0, stream>>>(Y1b, offs, csr, b1, Hb);
    // Zb = bf16(Hb @ W23b^T) : [8192,256]x[128,256]^T -> [8192,128]
    gemm_nt_mfma<4, 1, 4><<<dim3(128, 2), 256, 0, stream>>>(Hb, W23b, Zb, 128, 256);
    // mu/logvar = agg(Zb) + b2/b3 (split); zb = bf16(mu)
    agg_split_kernel<<<N_NODES / 4, 256, 0, stream>>>(Zb, offs, csr, b2, b3, mu_out, lv_out, zb);
    // adj = sigmoid(zb @ zb^T) via MFMA
    adj_mfma_kernel<<<dim3(64, 64), 256, 0, stream>>>(zb, adj);
}